// Round 13
// baseline (226.076 us; speedup 1.0000x reference)
//
#include <hip/hip_runtime.h>
#include <hip/hip_bf16.h>

#define DEVI __device__ __forceinline__

typedef __attribute__((ext_vector_type(8))) short bf16x8;
typedef __attribute__((ext_vector_type(16))) float f32x16;
typedef __attribute__((ext_vector_type(4))) unsigned int u32x4;
typedef __attribute__((ext_vector_type(4))) float fl4;

DEVI unsigned short f2bf(float f) {
  union { float f; unsigned u; } x; x.f = f;
  unsigned r = (x.u + 0x7fffu + ((x.u >> 16) & 1u)) >> 16;
  return (unsigned short)r;
}

DEVI unsigned cvtpk(float lo, float hi) {
  unsigned r;
  asm("v_cvt_pk_bf16_f32 %0, %1, %2" : "=v"(r) : "v"(lo), "v"(hi));
  return r;
}

DEVI float fadd3(float a, float b, float c) {
  return __fadd_rn(__fadd_rn(a, b), c);
}

// A/B image layout per 32KB K-step block (mfma_32x32x16):
//   addr(row, k) = (k>>3)*4096 + row*16 + (k&7)*2
// frag read: base + ks*8192 + (lane>>5)*4096 + (rowbase+(lane&31))*16
// (32 lanes x consecutive 16B: conflict-free in LDS, coalesced from global).
// A-image rows with kslot 12-15 are NEVER written; epilogue excludes them.

// ---------------------------------------------------------------- prep + fps
__global__ __launch_bounds__(256) void prep_fps_kernel(
    const float* __restrict__ Ws, const float* __restrict__ Wt0,
    const float* __restrict__ Wt123,
    const float* __restrict__ bWs, const float* __restrict__ gs,
    const float* __restrict__ bes, const float* __restrict__ mus,
    const float* __restrict__ vs,
    const float* __restrict__ bWt, const float* __restrict__ gt,
    const float* __restrict__ bet, const float* __restrict__ mut,
    const float* __restrict__ vt, const float* __restrict__ xt3,
    char* __restrict__ wbf, float* __restrict__ bnA, float* __restrict__ bnB,
    float* __restrict__ newxyz) {
  if (blockIdx.x >= 11296u) {
    const int b = blockIdx.x - 11296;
    const int t = threadIdx.x;
    if (t >= 64) return;
    const float* P = xt3 + (size_t)b * 256 * 3;
    float px[4], py[4], pz[4], d2[4];
#pragma unroll
    for (int j = 0; j < 4; ++j) {
      int p = t + 64 * j;
      px[j] = P[p * 3 + 0]; py[j] = P[p * 3 + 1]; pz[j] = P[p * 3 + 2];
      d2[j] = 1e10f;
    }
    float* NX = newxyz + (size_t)b * 64 * 3;
    float cx = __shfl(px[0], 0), cy = __shfl(py[0], 0), cz = __shfl(pz[0], 0);
    if (t == 0) { NX[0] = cx; NX[1] = cy; NX[2] = cz; }
    for (int i = 1; i < 64; ++i) {
      float bv = -1.0f; int bi = 0;
#pragma unroll
      for (int j = 0; j < 4; ++j) {
        float dx = __fsub_rn(px[j], cx), dy = __fsub_rn(py[j], cy),
              dz = __fsub_rn(pz[j], cz);
        float d = fadd3(__fmul_rn(dx, dx), __fmul_rn(dy, dy), __fmul_rn(dz, dz));
        d2[j] = fminf(d2[j], d);
        int p = t + 64 * j;
        if (j == 0) { bv = d2[0]; bi = t; }
        else if (d2[j] > bv) { bv = d2[j]; bi = p; }
      }
#pragma unroll
      for (int off = 32; off >= 1; off >>= 1) {
        float ov = __shfl_xor(bv, off);
        int oi = __shfl_xor(bi, off);
        if (ov > bv || (ov == bv && oi < bi)) { bv = ov; bi = oi; }
      }
      int s = bi;
      int owner = s & 63, slot = s >> 6;
      float sx = slot == 0 ? px[0] : slot == 1 ? px[1] : slot == 2 ? px[2] : px[3];
      float sy = slot == 0 ? py[0] : slot == 1 ? py[1] : slot == 2 ? py[2] : py[3];
      float sz = slot == 0 ? pz[0] : slot == 1 ? pz[1] : slot == 2 ? pz[2] : pz[3];
      cx = __shfl(sx, owner); cy = __shfl(sy, owner); cz = __shfl(sz, owner);
      if (t == 0) { NX[i * 3 + 0] = cx; NX[i * 3 + 1] = cy; NX[i * 3 + 2] = cz; }
    }
    return;
  }
  const unsigned id = blockIdx.x * 256u + threadIdx.x;
  const unsigned WN = 2883584u;
  if (id < WN) {
    float val; unsigned c, o, k, woffE;
    if (id < 1048576u) {
      c = id >> 18; unsigned rem = id & 262143u;
      o = rem >> 8; k = rem & 255u; val = Ws[id]; woffE = c << 18;
    } else if (id < 2097152u) {
      c = 4u; unsigned rem = id - 1048576u;
      o = rem >> 10; k = rem & 1023u; val = Wt0[rem]; woffE = 1048576u;
    } else {
      unsigned rem = id - 2097152u; unsigned cc = rem >> 18;
      c = 5u + cc; unsigned r2 = rem & 262143u;
      o = r2 >> 8; k = r2 & 255u; val = Wt123[rem];
      woffE = 2097152u + (cc << 18);
    }
    unsigned NKT = (c == 4u) ? 16u : 4u;
    unsigned ntile = o >> 8, op = o & 255u, kt = k >> 6, kl = k & 63u;
    unsigned byteoff = (woffE << 1) + ((ntile * NKT + kt) << 15) +
                       (kl >> 3) * 4096u + op * 16u + (kl & 7u) * 2u;
    *(unsigned short*)(wbf + byteoff) = f2bf(val);
  } else {
    unsigned r = id - WN;
    unsigned c = r >> 10, o = r & 1023u;
    float g, bW, mu, v, be;
    if (c < 4u) { g = gs[r]; bW = bWs[r]; mu = mus[r]; v = vs[r]; be = bes[r]; }
    else {
      unsigned r2 = (c - 4u) * 1024u + o;
      g = gt[r2]; bW = bWt[r2]; mu = mut[r2]; v = vt[r2]; be = bet[r2];
    }
    float A = g / sqrtf(v + 1e-5f);
    float B = (bW - mu) * A + be;
    bnA[r] = A; bnB[r] = B;
  }
}

// ---------------------------------------------------------------- KNN
template <int NJ>
DEVI void knn_run(int lane, const float* __restrict__ X, float qx, float qy,
                  float qz, float qq, int* __restrict__ out) {
  float d2[NJ];
#pragma unroll
  for (int j = 0; j < NJ; ++j) {
    int pi = lane + 64 * j;
    float x = X[pi * 3 + 0], y = X[pi * 3 + 1], z = X[pi * 3 + 2];
    float xx = fadd3(__fmul_rn(x, x), __fmul_rn(y, y), __fmul_rn(z, z));
    float dot = fadd3(__fmul_rn(qx, x), __fmul_rn(qy, y), __fmul_rn(qz, z));
    d2[j] = __fadd_rn(__fsub_rn(qq, __fmul_rn(2.0f, dot)), xx);
  }
  for (int kk = 0; kk < 12; ++kk) {
    float bv = d2[0]; int bi = lane;
#pragma unroll
    for (int j = 1; j < NJ; ++j) {
      if (d2[j] < bv) { bv = d2[j]; bi = lane + 64 * j; }
    }
#pragma unroll
    for (int off = 1; off <= 32; off <<= 1) {
      float ov = __shfl_xor(bv, off);
      int oi = __shfl_xor(bi, off);
      if (ov < bv || (ov == bv && oi < bi)) { bv = ov; bi = oi; }
    }
    if (lane == 0) out[kk] = bi;
#pragma unroll
    for (int j = 0; j < NJ; ++j)
      if (bi == lane + 64 * j) d2[j] = 3.4e38f;
  }
}

struct KnnP { const float* xyz[8]; };

__global__ __launch_bounds__(256) void knn_kernel(KnnP p,
                                                  const float* __restrict__ newxyz,
                                                  int* __restrict__ idxbuf) {
  const int q = blockIdx.x * 4 + (threadIdx.x >> 6);
  const int lane = threadIdx.x & 63;
  const int c = q >> 10, b = (q >> 6) & 15, g = q & 63;
  const int n = 2048 >> (c & 3);
  const float* X = p.xyz[c] + (size_t)b * n * 3;
  const float* qp = newxyz + ((size_t)b * 64 + g) * 3;
  float qx = qp[0], qy = qp[1], qz = qp[2];
  float qq = fadd3(__fmul_rn(qx, qx), __fmul_rn(qy, qy), __fmul_rn(qz, qz));
  int* out = idxbuf + (size_t)q * 12;
  switch (c & 3) {
    case 0: knn_run<32>(lane, X, qx, qy, qz, qq, out); break;
    case 1: knn_run<16>(lane, X, qx, qy, qz, qq, out); break;
    case 2: knn_run<8>(lane, X, qx, qy, qz, qq, out); break;
    default: knn_run<4>(lane, X, qx, qy, qz, qq, out); break;
  }
}

// ---------------------------------------------------------------- gather -> image
struct GImgP {
  const float* feat[8];
  int n[8];
  int K[8];
  int NKT[8];
  unsigned goffB[8];
  unsigned base[9];
};

__global__ __launch_bounds__(256) void gather_img_kernel(
    GImgP p, const int* __restrict__ idxbuf, char* __restrict__ grouped) {
  const unsigned blk = blockIdx.x;
  int c = 0;
#pragma unroll
  for (int j = 1; j < 8; ++j) if (blk >= p.base[j]) c = j;
  const unsigned local = blk - p.base[c];
  const int NKT = p.NKT[c];
  const int mtile = local / NKT;
  const int kt = local - mtile * NKT;
  const int row = threadIdx.x;
  const int gl = row >> 4, kslot = row & 15;
  if (kslot >= 12) return;
  const int group = mtile * 16 + gl;
  const int b = group >> 6;
  const int pidx = idxbuf[(size_t)c * 12288 + group * 12 + kslot];
  const int K = p.K[c];
  const float* src = p.feat[c] + ((size_t)b * p.n[c] + pidx) * K + kt * 64;
  char* dst = grouped + p.goffB[c] + ((size_t)(mtile * NKT + kt)) * 32768u +
              row * 16;
#pragma unroll
  for (int s = 0; s < 8; ++s) {
    fl4 v0 = *reinterpret_cast<const fl4*>(src + s * 8);
    fl4 v1 = *reinterpret_cast<const fl4*>(src + s * 8 + 4);
    u32x4 w;
    w[0] = cvtpk(v0[0], v0[1]);
    w[1] = cvtpk(v0[2], v0[3]);
    w[2] = cvtpk(v1[0], v1[1]);
    w[3] = cvtpk(v1[2], v1[3]);
    *reinterpret_cast<u32x4*>(dst + s * 4096) = w;
  }
}

// ---------------------------------------------------------------- persistent GEMM
// 256 blocks (1/CU), 16 waves (4Mx4N, per-wave 64x64), mfma_f32_32x32x16_bf16.
// Port split: A staged via global_load_lds into LDS (4x wc-reuse through LDS
// port); B read DIRECTLY from global image (coalesced 16B/lane; 32KB/step =
// L1-resident, 4x wr-reuse via L1) -> LDS, VMEM, and MFMA pipes balanced
// instead of all operand bytes on the LDS port.
struct GemmPR {
  unsigned goff[8]; unsigned woff[8]; unsigned outoff[8];
  unsigned bnoff[8]; int K[8];
};

#define GLOAD_LDS16(gsrc, ldsdst)                                              \
  __builtin_amdgcn_global_load_lds(                                            \
      (const __attribute__((address_space(1))) void*)(gsrc),                   \
      (__attribute__((address_space(3))) void*)(ldsdst), 16, 0, 0)

__global__ __launch_bounds__(1024, 4) void gemm_pers_kernel(
    const char* __restrict__ grouped, const char* __restrict__ wbf,
    const float* __restrict__ bnA, const float* __restrict__ bnB,
    float* __restrict__ out, GemmPR p) {
  extern __shared__ char smem[];  // 2 x [A 32K]
  const int bid = blockIdx.x;
  const int xcd = bid & 7, slot = bid >> 3;
  const int rem = (xcd << 5) | slot;
  const int mtile = rem >> 2, ntile = rem & 3;
  const int tid = threadIdx.x;
  const int lane = tid & 63, wid = tid >> 6;   // wid 0..15
  const int wr = wid >> 2, wc = wid & 3;

  const int aoff = (lane >> 5) * 4096 + (wr * 64 + (lane & 31)) * 16;
  const int boff = (lane >> 5) * 4096 + (wc * 64 + (lane & 31)) * 16;

  f32x16 acc[2][2];
#pragma unroll
  for (int j = 0; j < 2; ++j)
#pragma unroll
    for (int nn = 0; nn < 2; ++nn)
#pragma unroll
      for (int e = 0; e < 16; ++e) acc[j][nn][e] = 0.f;

  auto stageA = [&](int par, const char* src) {
    char* dst = smem + par * 32768;
#pragma unroll
    for (int it = 0; it < 2; ++it)
      GLOAD_LDS16(src + (it * 1024 + tid) * 16, dst + (it * 1024 + wid * 64) * 16);
  };

  int nkt = p.K[0] >> 6;
  const char* Ac = grouped + p.goff[0] + (size_t)mtile * nkt * 32768;
  const char* Bc = wbf + p.woff[0] + (size_t)ntile * nkt * 32768;

  stageA(0, Ac);
  __syncthreads();

  int gs = 0;
  for (int zi = 0; zi < 8; ++zi) {
    nkt = p.K[zi] >> 6;
    const char* An = nullptr;
    const char* Bn = nullptr;
    if (zi < 7) {
      int nktN = p.K[zi + 1] >> 6;
      An = grouped + p.goff[zi + 1] + (size_t)mtile * nktN * 32768;
      Bn = wbf + p.woff[zi + 1] + (size_t)ntile * nktN * 32768;
    }
    for (int kt = 0; kt < nkt; ++kt, ++gs) {
      const int par = gs & 1;
      const char* As = smem + par * 32768;
      const char* Bcur = Bc + (size_t)kt * 32768;   // global, L1-resident

      if (gs + 1 < 44) {
        int k1 = kt + 1;
        stageA(par ^ 1, (k1 < nkt) ? (Ac + (size_t)k1 * 32768) : An);
      }

      // B direct from global (VMEM/L1 pipe), coalesced 512B per half-wave
      bf16x8 bv[4][2];
#pragma unroll
      for (int ks = 0; ks < 4; ++ks)
#pragma unroll
        for (int nn = 0; nn < 2; ++nn)
          bv[ks][nn] = *reinterpret_cast<const bf16x8*>(
              Bcur + ks * 8192 + nn * 512 + boff);

      // A from LDS (LDS pipe)
      bf16x8 af[4][2];
#pragma unroll
      for (int ks = 0; ks < 4; ++ks)
#pragma unroll
        for (int j = 0; j < 2; ++j)
          af[ks][j] = *reinterpret_cast<const bf16x8*>(
              As + ks * 8192 + j * 512 + aoff);

#pragma unroll
      for (int ks = 0; ks < 4; ++ks)
#pragma unroll
        for (int j = 0; j < 2; ++j)
#pragma unroll
          for (int nn = 0; nn < 2; ++nn)
            acc[j][nn] = __builtin_amdgcn_mfma_f32_32x32x16_bf16(
                af[ks][j], bv[ks][nn], acc[j][nn], 0, 0, 0);

      __syncthreads();
    }

    // ---- epilogue tile zi: 32x32 C layout row=(reg&3)+8*(reg>>2)+4*(lane>>5).
    // hi=1 lanes' regs 4-7/12-15 hold rows 12-15 (padding) -> excluded.
    const float* bA = bnA + p.bnoff[zi];
    const float* bB = bnB + p.bnoff[zi];
    float* O = out + (size_t)p.outoff[zi];
    const bool hi0 = (lane < 32);
#pragma unroll
    for (int nn = 0; nn < 2; ++nn) {
      int colb = ntile * 256 + wc * 64 + nn * 32 + (lane & 31);
      float sA = bA[colb], sB = bB[colb];
#pragma unroll
      for (int j = 0; j < 2; ++j) {
#pragma unroll
        for (int h = 0; h < 2; ++h) {
          float v = fmaxf(fmaxf(acc[j][nn][8 * h + 0], acc[j][nn][8 * h + 1]),
                          fmaxf(acc[j][nn][8 * h + 2], acc[j][nn][8 * h + 3]));
          float v2 = fmaxf(fmaxf(acc[j][nn][8 * h + 4], acc[j][nn][8 * h + 5]),
                           fmaxf(acc[j][nn][8 * h + 6], acc[j][nn][8 * h + 7]));
          if (hi0) v = fmaxf(v, v2);
          v = fmaxf(v, __shfl_xor(v, 32));
          if (hi0) {
            int grp = mtile * 16 + wr * 4 + j * 2 + h;
            float val = fmaf(v, sA, sB);
            O[(size_t)grp * 1024 + colb] = fmaxf(val, 0.f);
          }
        }
      }
    }
#pragma unroll
    for (int j = 0; j < 2; ++j)
#pragma unroll
      for (int nn = 0; nn < 2; ++nn)
#pragma unroll
        for (int e = 0; e < 16; ++e) acc[j][nn][e] = 0.f;
    Ac = An;
    Bc = Bn;
  }
}

// ---------------------------------------------------------------- host
extern "C" void kernel_launch(void* const* d_in, const int* in_sizes, int n_in,
                              void* d_out, int out_size, void* d_ws,
                              size_t ws_size, hipStream_t stream) {
  (void)in_sizes; (void)n_in; (void)out_size; (void)ws_size;
  const float *fs[4], *xs[4], *ft[4], *xt[4];
  for (int i = 0; i < 4; ++i) {
    fs[i] = (const float*)d_in[4 * i + 0];
    xs[i] = (const float*)d_in[4 * i + 1];
    ft[i] = (const float*)d_in[4 * i + 2];
    xt[i] = (const float*)d_in[4 * i + 3];
  }
  const float* Ws = (const float*)d_in[16];
  const float* bWs = (const float*)d_in[17];
  const float* gs = (const float*)d_in[18];
  const float* bes = (const float*)d_in[19];
  const float* mus = (const float*)d_in[20];
  const float* vs = (const float*)d_in[21];
  const float* Wt0 = (const float*)d_in[22];
  const float* Wt123 = (const float*)d_in[23];
  const float* bWt = (const float*)d_in[24];
  const float* gt = (const float*)d_in[25];
  const float* bet = (const float*)d_in[26];
  const float* mut = (const float*)d_in[27];
  const float* vt = (const float*)d_in[28];

  char* ws = (char*)d_ws;
  float* newxyz = (float*)(ws + 0);
  int* idxbuf = (int*)(ws + 16384);
  float* bnA = (float*)(ws + 409600);
  float* bnB = (float*)(ws + 442368);
  char* wbf = ws + 475136;       // 5767168 B, B images
  char* grouped = ws + 6242304;  // 92274688 B, A images

  static const int NSarr[4] = {2048, 1024, 512, 256};
  const unsigned goffB[8] = {0u,        8388608u,  16777216u, 25165824u,
                             33554432u, 67108864u, 75497472u, 83886080u};
  const unsigned woffB[8] = {0u,       524288u,  1048576u, 1572864u,
                             2097152u, 4194304u, 4718592u, 5242880u};

  prep_fps_kernel<<<11312, 256, 0, stream>>>(Ws, Wt0, Wt123, bWs, gs, bes, mus,
                                             vs, bWt, gt, bet, mut, vt, xt[3],
                                             wbf, bnA, bnB, newxyz);

  KnnP kp;
  for (int i = 0; i < 4; ++i) {
    kp.xyz[i] = xs[i];
    kp.xyz[4 + i] = xt[i];
  }
  knn_kernel<<<2048, 256, 0, stream>>>(kp, newxyz, idxbuf);

  GImgP gp;
  unsigned cum = 0;
  for (int c = 0; c < 8; ++c) {
    int scale = c & 3;
    gp.feat[c] = (c < 4) ? fs[scale] : ft[scale];
    gp.n[c] = NSarr[scale];
    gp.K[c] = (c == 4) ? 1024 : 256;
    gp.NKT[c] = (c == 4) ? 16 : 4;
    gp.goffB[c] = goffB[c];
    gp.base[c] = cum;
    cum += 64u * (unsigned)gp.NKT[c];
  }
  gp.base[8] = cum;  // 2816 blocks
  gather_img_kernel<<<cum, 256, 0, stream>>>(gp, idxbuf, grouped);

  // zi order: light combos first, heavy (c=4, K=1024) last
  static const int co[8] = {0, 1, 2, 3, 5, 6, 7, 4};
  GemmPR mp;
  for (int zi = 0; zi < 8; ++zi) {
    int c = co[zi];
    mp.goff[zi] = goffB[c]; mp.woff[zi] = woffB[c];
    mp.outoff[zi] = (unsigned)c * 1048576u;
    mp.bnoff[zi] = (unsigned)c * 1024u;
    mp.K[zi] = (c == 4) ? 1024 : 256;
  }
  (void)hipFuncSetAttribute((const void*)gemm_pers_kernel,
                            hipFuncAttributeMaxDynamicSharedMemorySize, 65536);
  gemm_pers_kernel<<<256, 1024, 65536, stream>>>(grouped, wbf, bnA, bnB,
                                                 (float*)d_out, mp);
}

// Round 14
// 199.238 us; speedup vs baseline: 1.1347x; 1.1347x over previous
//
#include <hip/hip_runtime.h>
#include <hip/hip_bf16.h>

#define DEVI __device__ __forceinline__

typedef __attribute__((ext_vector_type(8))) short bf16x8;
typedef __attribute__((ext_vector_type(16))) float f32x16;
typedef __attribute__((ext_vector_type(4))) unsigned int u32x4;
typedef __attribute__((ext_vector_type(4))) float fl4;

DEVI unsigned short f2bf(float f) {
  union { float f; unsigned u; } x; x.f = f;
  unsigned r = (x.u + 0x7fffu + ((x.u >> 16) & 1u)) >> 16;
  return (unsigned short)r;
}

DEVI unsigned cvtpk(float lo, float hi) {
  unsigned r;
  asm("v_cvt_pk_bf16_f32 %0, %1, %2" : "=v"(r) : "v"(lo), "v"(hi));
  return r;
}

DEVI float fadd3(float a, float b, float c) {
  return __fadd_rn(__fadd_rn(a, b), c);
}

// A/B image layout per 32KB K-step block (mfma_32x32x16):
//   addr(row, k) = (k>>3)*4096 + row*16 + (k&7)*2
// frag read: base + ks*8192 + (lane>>5)*4096 + (rowbase+(lane&31))*16
// (32 lanes x consecutive 16B: conflict-free in LDS, coalesced writes).
// A-image rows with kslot 12-15 are NEVER written; epilogue excludes them.

// ---------------------------------------------------------------- prep2
// Grid 224 blocks: [0,176) B-image conversion (block per (c,ntile,kt), thread
// per output row, vectorized); [176,208) BN fold; [208,224) FPS.
__global__ __launch_bounds__(256) void prep2_kernel(
    const float* __restrict__ Ws, const float* __restrict__ Wt0,
    const float* __restrict__ Wt123,
    const float* __restrict__ bWs, const float* __restrict__ gs,
    const float* __restrict__ bes, const float* __restrict__ mus,
    const float* __restrict__ vs,
    const float* __restrict__ bWt, const float* __restrict__ gt,
    const float* __restrict__ bet, const float* __restrict__ mut,
    const float* __restrict__ vt, const float* __restrict__ xt3,
    char* __restrict__ wbf, float* __restrict__ bnA, float* __restrict__ bnB,
    float* __restrict__ newxyz) {
  const int blk = blockIdx.x;
  const int t = threadIdx.x;
  if (blk < 176) {
    // ---- B-image conversion
    int c, ntile, kt, NKT;
    if (blk < 64) { c = 4; NKT = 16; ntile = blk >> 4; kt = blk & 15; }
    else {
      int idx = blk - 64;
      int c7 = idx >> 4; c = (c7 < 4) ? c7 : c7 + 1;
      NKT = 4; ntile = (idx >> 2) & 3; kt = idx & 3;
    }
    const int o = ntile * 256 + t;
    const float* src;
    if (c < 4) src = Ws + (size_t)c * 262144 + o * 256 + kt * 64;
    else if (c == 4) src = Wt0 + (size_t)o * 1024 + kt * 64;
    else src = Wt123 + (size_t)(c - 5) * 262144 + o * 256 + kt * 64;
    const unsigned woffB[8] = {0u,       524288u,  1048576u, 1572864u,
                               2097152u, 4194304u, 4718592u, 5242880u};
    char* dst = wbf + woffB[c] + (size_t)(ntile * NKT + kt) * 32768u + t * 16;
#pragma unroll
    for (int s = 0; s < 8; ++s) {
      fl4 v0 = *reinterpret_cast<const fl4*>(src + s * 8);
      fl4 v1 = *reinterpret_cast<const fl4*>(src + s * 8 + 4);
      u32x4 w;
      w[0] = cvtpk(v0[0], v0[1]);
      w[1] = cvtpk(v0[2], v0[3]);
      w[2] = cvtpk(v1[0], v1[1]);
      w[3] = cvtpk(v1[2], v1[3]);
      *reinterpret_cast<u32x4*>(dst + s * 4096) = w;
    }
    return;
  }
  if (blk < 208) {
    // ---- BN fold
    unsigned r = (unsigned)(blk - 176) * 256u + t;
    unsigned c = r >> 10, o = r & 1023u;
    float g, bW, mu, v, be;
    if (c < 4u) { g = gs[r]; bW = bWs[r]; mu = mus[r]; v = vs[r]; be = bes[r]; }
    else {
      unsigned r2 = (c - 4u) * 1024u + o;
      g = gt[r2]; bW = bWt[r2]; mu = mut[r2]; v = vt[r2]; be = bet[r2];
    }
    float A = g / sqrtf(v + 1e-5f);
    float B = (bW - mu) * A + be;
    bnA[r] = A; bnB[r] = B;
    return;
  }
  // ---- FPS: one wave per batch
  const int b = blk - 208;
  if (t >= 64) return;
  const float* P = xt3 + (size_t)b * 256 * 3;
  float px[4], py[4], pz[4], d2[4];
#pragma unroll
  for (int j = 0; j < 4; ++j) {
    int p = t + 64 * j;
    px[j] = P[p * 3 + 0]; py[j] = P[p * 3 + 1]; pz[j] = P[p * 3 + 2];
    d2[j] = 1e10f;
  }
  float* NX = newxyz + (size_t)b * 64 * 3;
  float cx = __shfl(px[0], 0), cy = __shfl(py[0], 0), cz = __shfl(pz[0], 0);
  if (t == 0) { NX[0] = cx; NX[1] = cy; NX[2] = cz; }
  for (int i = 1; i < 64; ++i) {
    float bv = -1.0f; int bi = 0;
#pragma unroll
    for (int j = 0; j < 4; ++j) {
      float dx = __fsub_rn(px[j], cx), dy = __fsub_rn(py[j], cy),
            dz = __fsub_rn(pz[j], cz);
      float d = fadd3(__fmul_rn(dx, dx), __fmul_rn(dy, dy), __fmul_rn(dz, dz));
      d2[j] = fminf(d2[j], d);
      int p = t + 64 * j;
      if (j == 0) { bv = d2[0]; bi = t; }
      else if (d2[j] > bv) { bv = d2[j]; bi = p; }
    }
#pragma unroll
    for (int off = 32; off >= 1; off >>= 1) {
      float ov = __shfl_xor(bv, off);
      int oi = __shfl_xor(bi, off);
      if (ov > bv || (ov == bv && oi < bi)) { bv = ov; bi = oi; }
    }
    int s = bi;
    int owner = s & 63, slot = s >> 6;
    float sx = slot == 0 ? px[0] : slot == 1 ? px[1] : slot == 2 ? px[2] : px[3];
    float sy = slot == 0 ? py[0] : slot == 1 ? py[1] : slot == 2 ? py[2] : py[3];
    float sz = slot == 0 ? pz[0] : slot == 1 ? pz[1] : slot == 2 ? pz[2] : pz[3];
    cx = __shfl(sx, owner); cy = __shfl(sy, owner); cz = __shfl(sz, owner);
    if (t == 0) { NX[i * 3 + 0] = cx; NX[i * 3 + 1] = cy; NX[i * 3 + 2] = cz; }
  }
}

// ---------------------------------------------------------------- KNN + gather v2
// 2048 blocks x 4 waves; wave w computes KNN for query g0+w (parallel, same as
// standalone knn), indices -> LDS; then all 256 threads write the 4 groups'
// 64 consecutive image rows coalesced. Heavy c=4 blocks scheduled first.
template <int NJ>
DEVI void knn_run(int lane, const float* __restrict__ X, float qx, float qy,
                  float qz, float qq, int* __restrict__ out) {
  float d2[NJ];
#pragma unroll
  for (int j = 0; j < NJ; ++j) {
    int pi = lane + 64 * j;
    float x = X[pi * 3 + 0], y = X[pi * 3 + 1], z = X[pi * 3 + 2];
    float xx = fadd3(__fmul_rn(x, x), __fmul_rn(y, y), __fmul_rn(z, z));
    float dot = fadd3(__fmul_rn(qx, x), __fmul_rn(qy, y), __fmul_rn(qz, z));
    d2[j] = __fadd_rn(__fsub_rn(qq, __fmul_rn(2.0f, dot)), xx);
  }
  for (int kk = 0; kk < 12; ++kk) {
    float bv = d2[0]; int bi = lane;
#pragma unroll
    for (int j = 1; j < NJ; ++j) {
      if (d2[j] < bv) { bv = d2[j]; bi = lane + 64 * j; }
    }
#pragma unroll
    for (int off = 1; off <= 32; off <<= 1) {
      float ov = __shfl_xor(bv, off);
      int oi = __shfl_xor(bi, off);
      if (ov < bv || (ov == bv && oi < bi)) { bv = ov; bi = oi; }
    }
    if (lane == 0) out[kk] = bi;
#pragma unroll
    for (int j = 0; j < NJ; ++j)
      if (bi == lane + 64 * j) d2[j] = 3.4e38f;
  }
}

struct KGP {
  const float* feat[8];
  const float* xyz[8];
  unsigned goffB[8];
};

__global__ __launch_bounds__(256) void knn_gather2_kernel(
    KGP p, const float* __restrict__ newxyz, char* __restrict__ grouped) {
  const int blk = blockIdx.x;
  int c, q0;
  if (blk < 256) { c = 4; q0 = 4096 + blk * 4; }      // heavy combo first
  else {
    int idx = blk - 256;
    int c7 = idx >> 8; c = (c7 < 4) ? c7 : c7 + 1;
    q0 = c * 1024 + (idx & 255) * 4;
  }
  const int scale = c & 3;
  const int n = 2048 >> scale;
  const int b = (q0 >> 6) & 15;
  const int g0 = q0 & 63;
  const int wid = threadIdx.x >> 6, lane = threadIdx.x & 63;
  __shared__ int idxs[4][12];
  const float* X = p.xyz[c] + (size_t)b * n * 3;
  {
    const int g = g0 + wid;
    const float* qp = newxyz + ((size_t)b * 64 + g) * 3;
    float qx = qp[0], qy = qp[1], qz = qp[2];
    float qq = fadd3(__fmul_rn(qx, qx), __fmul_rn(qy, qy), __fmul_rn(qz, qz));
    switch (scale) {
      case 0: knn_run<32>(lane, X, qx, qy, qz, qq, idxs[wid]); break;
      case 1: knn_run<16>(lane, X, qx, qy, qz, qq, idxs[wid]); break;
      case 2: knn_run<8>(lane, X, qx, qy, qz, qq, idxs[wid]); break;
      default: knn_run<4>(lane, X, qx, qy, qz, qq, idxs[wid]); break;
    }
  }
  __syncthreads();

  const int r = threadIdx.x & 63;       // row within the 4-group span
  const int sgrp = threadIdx.x >> 6;    // this thread's 2 s-chunks
  const int gl = r >> 4, kslot = r & 15;
  if (kslot >= 12) return;              // padding rows: never written
  const int K = (c == 4) ? 1024 : 256;
  const int NKT = K >> 6;
  const int mtile = b * 4 + (g0 >> 4);
  const int rowT = (g0 & 15) * 16 + r;  // row in 256-row image
  const int pidx = idxs[gl][kslot];
  const float* rowp = p.feat[c] + ((size_t)b * n + pidx) * K;
  char* dstb = grouped + p.goffB[c] + (size_t)mtile * NKT * 32768u + rowT * 16;
  for (int kt = 0; kt < NKT; ++kt) {
    char* dkt = dstb + (size_t)kt * 32768u;
    const float* skt = rowp + kt * 64;
#pragma unroll
    for (int ss = 0; ss < 2; ++ss) {
      int s = sgrp * 2 + ss;
      fl4 v0 = *reinterpret_cast<const fl4*>(skt + s * 8);
      fl4 v1 = *reinterpret_cast<const fl4*>(skt + s * 8 + 4);
      u32x4 w;
      w[0] = cvtpk(v0[0], v0[1]);
      w[1] = cvtpk(v0[2], v0[3]);
      w[2] = cvtpk(v1[0], v1[1]);
      w[3] = cvtpk(v1[2], v1[3]);
      *reinterpret_cast<u32x4*>(dkt + s * 4096) = w;
    }
  }
}

// ---------------------------------------------------------------- persistent GEMM
// (R12's best: 103 us, MfmaUtil ~39%.) 256 blocks (1/CU), 16 waves (4Mx4N,
// per-wave 64x64), mfma_f32_32x32x16_bf16, A+B in LDS dbuf, depth-1 stage,
// 1 barrier/step, 44 continuous K-steps across all 8 combos.
struct GemmPR {
  unsigned goff[8]; unsigned woff[8]; unsigned outoff[8];
  unsigned bnoff[8]; int K[8];
};

#define GLOAD_LDS16(gsrc, ldsdst)                                              \
  __builtin_amdgcn_global_load_lds(                                            \
      (const __attribute__((address_space(1))) void*)(gsrc),                   \
      (__attribute__((address_space(3))) void*)(ldsdst), 16, 0, 0)

__global__ __launch_bounds__(1024, 4) void gemm_pers_kernel(
    const char* __restrict__ grouped, const char* __restrict__ wbf,
    const float* __restrict__ bnA, const float* __restrict__ bnB,
    float* __restrict__ out, GemmPR p) {
  extern __shared__ char smem[];  // 2 x [A 32K | B 32K]
  const int bid = blockIdx.x;
  const int xcd = bid & 7, slot = bid >> 3;
  const int rem = (xcd << 5) | slot;
  const int mtile = rem >> 2, ntile = rem & 3;
  const int tid = threadIdx.x;
  const int lane = tid & 63, wid = tid >> 6;   // wid 0..15
  const int wr = wid >> 2, wc = wid & 3;

  const int aoff = (lane >> 5) * 4096 + (wr * 64 + (lane & 31)) * 16;
  const int boff = (lane >> 5) * 4096 + (wc * 64 + (lane & 31)) * 16;

  f32x16 acc[2][2];
#pragma unroll
  for (int j = 0; j < 2; ++j)
#pragma unroll
    for (int nn = 0; nn < 2; ++nn)
#pragma unroll
      for (int e = 0; e < 16; ++e) acc[j][nn][e] = 0.f;

  auto stageA = [&](int par, const char* src) {
    char* dst = smem + par * 65536;
#pragma unroll
    for (int it = 0; it < 2; ++it)
      GLOAD_LDS16(src + (it * 1024 + tid) * 16, dst + (it * 1024 + wid * 64) * 16);
  };
  auto stageB = [&](int par, const char* src) {
    char* dst = smem + par * 65536 + 32768;
#pragma unroll
    for (int it = 0; it < 2; ++it)
      GLOAD_LDS16(src + (it * 1024 + tid) * 16, dst + (it * 1024 + wid * 64) * 16);
  };

  int nkt = p.K[0] >> 6;
  const char* Ac = grouped + p.goff[0] + (size_t)mtile * nkt * 32768;
  const char* Bc = wbf + p.woff[0] + (size_t)ntile * nkt * 32768;

  stageA(0, Ac);
  stageB(0, Bc);
  __syncthreads();

  int gs = 0;
  for (int zi = 0; zi < 8; ++zi) {
    nkt = p.K[zi] >> 6;
    const char* An = nullptr;
    const char* Bn = nullptr;
    if (zi < 7) {
      int nktN = p.K[zi + 1] >> 6;
      An = grouped + p.goff[zi + 1] + (size_t)mtile * nktN * 32768;
      Bn = wbf + p.woff[zi + 1] + (size_t)ntile * nktN * 32768;
    }
    for (int kt = 0; kt < nkt; ++kt, ++gs) {
      const int par = gs & 1;
      const char* As = smem + par * 65536;
      const char* Bs = As + 32768;

      if (gs + 1 < 44) {
        int k1 = kt + 1;
        const char* sA, * sB;
        if (k1 < nkt) { sA = Ac + (size_t)k1 * 32768; sB = Bc + (size_t)k1 * 32768; }
        else { sA = An; sB = Bn; }
        stageA(par ^ 1, sA);
        stageB(par ^ 1, sB);
      }

      bf16x8 bv[4][2], af[4][2];
#pragma unroll
      for (int ks = 0; ks < 4; ++ks)
#pragma unroll
        for (int nn = 0; nn < 2; ++nn)
          bv[ks][nn] = *reinterpret_cast<const bf16x8*>(
              Bs + ks * 8192 + nn * 512 + boff);
#pragma unroll
      for (int ks = 0; ks < 4; ++ks)
#pragma unroll
        for (int j = 0; j < 2; ++j)
          af[ks][j] = *reinterpret_cast<const bf16x8*>(
              As + ks * 8192 + j * 512 + aoff);
#pragma unroll
      for (int ks = 0; ks < 4; ++ks)
#pragma unroll
        for (int j = 0; j < 2; ++j)
#pragma unroll
          for (int nn = 0; nn < 2; ++nn)
            acc[j][nn] = __builtin_amdgcn_mfma_f32_32x32x16_bf16(
                af[ks][j], bv[ks][nn], acc[j][nn], 0, 0, 0);

      __syncthreads();
    }

    // ---- epilogue tile zi: 32x32 C layout row=(reg&3)+8*(reg>>2)+4*(lane>>5).
    // hi=1 lanes' regs 4-7/12-15 hold rows 12-15 (padding) -> excluded.
    const float* bA = bnA + p.bnoff[zi];
    const float* bB = bnB + p.bnoff[zi];
    float* O = out + (size_t)p.outoff[zi];
    const bool hi0 = (lane < 32);
#pragma unroll
    for (int nn = 0; nn < 2; ++nn) {
      int colb = ntile * 256 + wc * 64 + nn * 32 + (lane & 31);
      float sA = bA[colb], sB = bB[colb];
#pragma unroll
      for (int j = 0; j < 2; ++j) {
#pragma unroll
        for (int h = 0; h < 2; ++h) {
          float v = fmaxf(fmaxf(acc[j][nn][8 * h + 0], acc[j][nn][8 * h + 1]),
                          fmaxf(acc[j][nn][8 * h + 2], acc[j][nn][8 * h + 3]));
          float v2 = fmaxf(fmaxf(acc[j][nn][8 * h + 4], acc[j][nn][8 * h + 5]),
                           fmaxf(acc[j][nn][8 * h + 6], acc[j][nn][8 * h + 7]));
          if (hi0) v = fmaxf(v, v2);
          v = fmaxf(v, __shfl_xor(v, 32));
          if (hi0) {
            int grp = mtile * 16 + wr * 4 + j * 2 + h;
            float val = fmaf(v, sA, sB);
            O[(size_t)grp * 1024 + colb] = fmaxf(val, 0.f);
          }
        }
      }
    }
#pragma unroll
    for (int j = 0; j < 2; ++j)
#pragma unroll
      for (int nn = 0; nn < 2; ++nn)
#pragma unroll
        for (int e = 0; e < 16; ++e) acc[j][nn][e] = 0.f;
    Ac = An;
    Bc = Bn;
  }
}

// ---------------------------------------------------------------- host
extern "C" void kernel_launch(void* const* d_in, const int* in_sizes, int n_in,
                              void* d_out, int out_size, void* d_ws,
                              size_t ws_size, hipStream_t stream) {
  (void)in_sizes; (void)n_in; (void)out_size; (void)ws_size;
  const float *fs[4], *xs[4], *ft[4], *xt[4];
  for (int i = 0; i < 4; ++i) {
    fs[i] = (const float*)d_in[4 * i + 0];
    xs[i] = (const float*)d_in[4 * i + 1];
    ft[i] = (const float*)d_in[4 * i + 2];
    xt[i] = (const float*)d_in[4 * i + 3];
  }
  const float* Ws = (const float*)d_in[16];
  const float* bWs = (const float*)d_in[17];
  const float* gs = (const float*)d_in[18];
  const float* bes = (const float*)d_in[19];
  const float* mus = (const float*)d_in[20];
  const float* vs = (const float*)d_in[21];
  const float* Wt0 = (const float*)d_in[22];
  const float* Wt123 = (const float*)d_in[23];
  const float* bWt = (const float*)d_in[24];
  const float* gt = (const float*)d_in[25];
  const float* bet = (const float*)d_in[26];
  const float* mut = (const float*)d_in[27];
  const float* vt = (const float*)d_in[28];

  char* ws = (char*)d_ws;
  float* newxyz = (float*)(ws + 0);
  float* bnA = (float*)(ws + 409600);
  float* bnB = (float*)(ws + 442368);
  char* wbf = ws + 475136;       // 5767168 B, B images
  char* grouped = ws + 6242304;  // 92274688 B, A images

  const unsigned goffB[8] = {0u,        8388608u,  16777216u, 25165824u,
                             33554432u, 67108864u, 75497472u, 83886080u};
  const unsigned woffB[8] = {0u,       524288u,  1048576u, 1572864u,
                             2097152u, 4194304u, 4718592u, 5242880u};

  prep2_kernel<<<224, 256, 0, stream>>>(Ws, Wt0, Wt123, bWs, gs, bes, mus, vs,
                                        bWt, gt, bet, mut, vt, xt[3], wbf, bnA,
                                        bnB, newxyz);

  KGP kg;
  for (int c = 0; c < 8; ++c) {
    int scale = c & 3;
    kg.feat[c] = (c < 4) ? fs[scale] : ft[scale];
    kg.xyz[c] = (c < 4) ? xs[scale] : xt[scale];
    kg.goffB[c] = goffB[c];
  }
  knn_gather2_kernel<<<2048, 256, 0, stream>>>(kg, newxyz, grouped);

  // zi order: light combos first, heavy (c=4, K=1024) last
  static const int co[8] = {0, 1, 2, 3, 5, 6, 7, 4};
  GemmPR mp;
  for (int zi = 0; zi < 8; ++zi) {
    int c = co[zi];
    mp.goff[zi] = goffB[c]; mp.woff[zi] = woffB[c];
    mp.outoff[zi] = (unsigned)c * 1048576u;
    mp.bnoff[zi] = (unsigned)c * 1024u;
    mp.K[zi] = (c == 4) ? 1024 : 256;
  }
  (void)hipFuncSetAttribute((const void*)gemm_pers_kernel,
                            hipFuncAttributeMaxDynamicSharedMemorySize, 131072);
  gemm_pers_kernel<<<256, 1024, 131072, stream>>>(grouped, wbf, bnA, bnB,
                                                  (float*)d_out, mp);
}